// Round 1
// baseline (303.943 us; speedup 1.0000x reference)
//
#include <hip/hip_runtime.h>

// DCNv2 forward, fp32. Fixed problem size from the reference:
#define N_    4
#define C_    64
#define H_    128
#define W_    128
#define KH_   3
#define KW_   3
#define K_    9       // KH*KW
#define COUT_ 64
#define HW_   (H_ * W_)   // 16384

// ---------------------------------------------------------------------------
// Prologue: transpose weight[o][c][k] (Cout,C,K) -> wT[(c*K+k)*COUT + o]
// so the hot loop's 64 uniform weight reads are contiguous (s_load_dwordx16).
// ---------------------------------------------------------------------------
__global__ void transpose_weight(const float* __restrict__ w,
                                 float* __restrict__ wT) {
    int tid = blockIdx.x * blockDim.x + threadIdx.x;   // 0 .. 36863
    if (tid >= COUT_ * C_ * K_) return;
    int o  = tid & (COUT_ - 1);   // fastest: output channel
    int ck = tid >> 6;            // c*K + k
    wT[tid] = w[o * (C_ * K_) + ck];
}

// ---------------------------------------------------------------------------
// Main kernel: one thread per output pixel, 64 accumulators (all out chans).
// TW = true: weights pre-transposed in d_ws (contiguous uniform loads).
// TW = false: fallback, read strided from original weight layout.
// ---------------------------------------------------------------------------
template <bool TW>
__global__ __launch_bounds__(256) void dcn_fwd(
    const float* __restrict__ x,       // (N, C, H, W)
    const float* __restrict__ offset,  // (N, 2*K, H, W)  ch = 2k (+0=y, +1=x)
    const float* __restrict__ mask,    // (N, K, H, W)
    const float* __restrict__ wptr,    // TW ? wT[ck*64+o] : weight[o*576+ck]
    const float* __restrict__ bias,    // (Cout,)
    float* __restrict__ out)           // (N, Cout, H, W)
{
    const int pix = blockIdx.x * 256 + threadIdx.x;    // 0 .. 65535
    const int n   = pix >> 14;          // / HW_
    const int hw  = pix & (HW_ - 1);
    const int ho  = hw >> 7;            // / W_
    const int wo  = hw & (W_ - 1);

    float acc[COUT_];
#pragma unroll
    for (int o = 0; o < COUT_; ++o) acc[o] = bias[o];

    const float* xn   = x      + n * (C_ * HW_);
    const float* offn = offset + n * (2 * K_ * HW_) + hw;
    const float* mn   = mask   + n * (K_ * HW_)     + hw;

    for (int k = 0; k < K_; ++k) {
        const int ky = k / KW_;
        const int kx = k - ky * KW_;

        const float off_y = offn[(2 * k + 0) * HW_];
        const float off_x = offn[(2 * k + 1) * HW_];
        const float m     = mn[k * HW_];

        const float py = (float)(ho - 1 + ky) + off_y;   // stride=1, pad=1, dil=1
        const float px = (float)(wo - 1 + kx) + off_x;

        const float y0f = floorf(py);
        const float x0f = floorf(px);
        const float ly  = py - y0f;
        const float lx  = px - x0f;

        const int y0 = (int)y0f, x0 = (int)x0f;
        const int y1 = y0 + 1,   x1 = x0 + 1;

        const bool vy0 = (y0 >= 0) && (y0 < H_);
        const bool vy1 = (y1 >= 0) && (y1 < H_);
        const bool vx0 = (x0 >= 0) && (x0 < W_);
        const bool vx1 = (x1 >= 0) && (x1 < W_);

        const int cy0 = min(max(y0, 0), H_ - 1);
        const int cy1 = min(max(y1, 0), H_ - 1);
        const int cx0 = min(max(x0, 0), W_ - 1);
        const int cx1 = min(max(x1, 0), W_ - 1);

        const int i00 = cy0 * W_ + cx0;
        const int i01 = cy0 * W_ + cx1;
        const int i10 = cy1 * W_ + cx0;
        const int i11 = cy1 * W_ + cx1;

        // fold validity + mask into the 4 bilinear corner coefficients
        const float f00 = (1.f - ly) * (1.f - lx) * m * ((vy0 && vx0) ? 1.f : 0.f);
        const float f01 = (1.f - ly) * lx         * m * ((vy0 && vx1) ? 1.f : 0.f);
        const float f10 = ly         * (1.f - lx) * m * ((vy1 && vx0) ? 1.f : 0.f);
        const float f11 = ly         * lx         * m * ((vy1 && vx1) ? 1.f : 0.f);

        for (int c = 0; c < C_; ++c) {
            const float* xc = xn + c * HW_;
            const float val = fmaf(f00, xc[i00],
                             fmaf(f01, xc[i01],
                             fmaf(f10, xc[i10],
                                  f11 * xc[i11])));
            const int ck = c * K_ + k;
            if (TW) {
                const float* wrow = wptr + ck * COUT_;   // contiguous, uniform
#pragma unroll
                for (int o = 0; o < COUT_; ++o)
                    acc[o] = fmaf(wrow[o], val, acc[o]);
            } else {
#pragma unroll
                for (int o = 0; o < COUT_; ++o)
                    acc[o] = fmaf(wptr[o * (C_ * K_) + ck], val, acc[o]);
            }
        }
    }

    float* outp = out + n * (COUT_ * HW_) + hw;
#pragma unroll
    for (int o = 0; o < COUT_; ++o) outp[o * HW_] = acc[o];
}

extern "C" void kernel_launch(void* const* d_in, const int* in_sizes, int n_in,
                              void* d_out, int out_size, void* d_ws, size_t ws_size,
                              hipStream_t stream) {
    const float* x      = (const float*)d_in[0];
    const float* offset = (const float*)d_in[1];
    const float* mask   = (const float*)d_in[2];
    const float* weight = (const float*)d_in[3];
    const float* bias   = (const float*)d_in[4];
    float* out = (float*)d_out;

    const size_t wT_bytes = (size_t)COUT_ * C_ * K_ * sizeof(float);  // 147456

    const int total_pix = N_ * HW_;           // 65536
    const int blocks    = total_pix / 256;    // 256

    if (ws_size >= wT_bytes) {
        float* wT = (float*)d_ws;
        transpose_weight<<<(COUT_ * C_ * K_ + 255) / 256, 256, 0, stream>>>(weight, wT);
        dcn_fwd<true><<<blocks, 256, 0, stream>>>(x, offset, mask, wT, bias, out);
    } else {
        dcn_fwd<false><<<blocks, 256, 0, stream>>>(x, offset, mask, weight, bias, out);
    }
}